// Round 2
// baseline (99.012 us; speedup 1.0000x reference)
//
#include <hip/hip_runtime.h>

#define B_  32
#define T_  4096
#define D_  256
#define D4_ 64   // D_/4 in float4 units

typedef float f32x4 __attribute__((ext_vector_type(4)));

__device__ __forceinline__ f32x4 sigmoid4(f32x4 v) {
    f32x4 r;
    r[0] = 1.0f / (1.0f + expf(-v[0]));
    r[1] = 1.0f / (1.0f + expf(-v[1]));
    r[2] = 1.0f / (1.0f + expf(-v[2]));
    r[3] = 1.0f / (1.0f + expf(-v[3]));
    return r;
}

// K1: per-chunk local scan (h = 0), write chunk-end state E[b][c][d]
__global__ __launch_bounds__(256) void ema_carry(
    const f32x4* __restrict__ x, const f32x4* __restrict__ la,
    f32x4* __restrict__ E, int NC, int L) {
    const int wid  = threadIdx.x >> 6;
    const int lane = threadIdx.x & 63;
    const int g = blockIdx.x * 4 + wid;        // chunk-task id in [0, B*NC)
    const int b = g / NC;
    const int c = g % NC;

    const f32x4 al = sigmoid4(la[lane]);
    const f32x4 om = 1.0f - al;

    size_t idx = ((size_t)b * T_ + (size_t)c * L) * D4_ + lane;
    f32x4 y = 0.0f;
    int i0 = 0;
    if (c == 0) {                               // y_0 = x_0 exactly
        y = x[idx];
        idx += D4_;
        i0 = 1;
    }
    #pragma unroll 4
    for (int i = i0; i < L; ++i) {
        f32x4 xv = x[idx]; idx += D4_;
        y = al * y + om * xv;
    }
    E[(size_t)g * D4_ + lane] = y;
}

// K2: sequential fold of carries per (b, d). Overwrites E with the
// INCOMING state H for each chunk: H_c = s_{c-1}, s_c = a^L * s_{c-1} + E_c.
__global__ __launch_bounds__(64) void ema_combine(
    const f32x4* __restrict__ la, f32x4* __restrict__ E,
    int NC, int log2L) {
    const int b = blockIdx.x;
    const int lane = threadIdx.x;

    const f32x4 al = sigmoid4(la[lane]);
    f32x4 p = al;                               // p = al^(2^log2L) = al^L
    for (int k = 0; k < log2L; ++k) p = p * p;

    f32x4 s = 0.0f;
    for (int c = 0; c < NC; ++c) {
        size_t o = ((size_t)b * NC + c) * D4_ + lane;
        f32x4 e = E[o];
        E[o] = s;                               // incoming state for chunk c
        s = p * s + e;
    }
}

// K3: re-run the recurrence per chunk from incoming state H, write y.
__global__ __launch_bounds__(256) void ema_apply(
    const f32x4* __restrict__ x, const f32x4* __restrict__ la,
    const f32x4* __restrict__ H, f32x4* __restrict__ yout,
    int NC, int L) {
    const int wid  = threadIdx.x >> 6;
    const int lane = threadIdx.x & 63;
    const int g = blockIdx.x * 4 + wid;
    const int b = g / NC;
    const int c = g % NC;

    const f32x4 al = sigmoid4(la[lane]);
    const f32x4 om = 1.0f - al;

    size_t idx = ((size_t)b * T_ + (size_t)c * L) * D4_ + lane;
    f32x4 acc;
    int i0 = 0;
    if (c == 0) {
        acc = x[idx];                           // y_0 = x_0
        __builtin_nontemporal_store(acc, &yout[idx]);
        idx += D4_;
        i0 = 1;
    } else {
        acc = H[(size_t)g * D4_ + lane];
    }
    #pragma unroll 4
    for (int i = i0; i < L; ++i) {
        f32x4 xv = x[idx];
        acc = al * acc + om * xv;
        __builtin_nontemporal_store(acc, &yout[idx]);
        idx += D4_;
    }
}

extern "C" void kernel_launch(void* const* d_in, const int* in_sizes, int n_in,
                              void* d_out, int out_size, void* d_ws, size_t ws_size,
                              hipStream_t stream) {
    const f32x4* x  = (const f32x4*)d_in[0];
    const f32x4* la = (const f32x4*)d_in[1];
    f32x4* out = (f32x4*)d_out;

    // Pick the largest power-of-2 chunk count that fits the E buffer in d_ws.
    int NC = 128;
    while (NC > 1 && (size_t)B_ * NC * D_ * sizeof(float) > ws_size) NC >>= 1;
    const int L = T_ / NC;
    int log2L = 0;
    while ((1 << log2L) < L) ++log2L;

    f32x4* E = (f32x4*)d_ws;
    const int ntasks = B_ * NC;                 // chunk-tasks, 4 per block
    dim3 blk(256);
    dim3 grd(ntasks / 4);

    ema_carry  <<<grd, blk, 0, stream>>>(x, la, E, NC, L);
    ema_combine<<<B_, 64, 0, stream>>>(la, E, NC, log2L);
    ema_apply  <<<grd, blk, 0, stream>>>(x, la, E, out, NC, L);
}